// Round 2
// baseline (936.336 us; speedup 1.0000x reference)
//
#include <hip/hip_runtime.h>
#include <math.h>

namespace {

constexpr int T = 8192;
constexpr int E = 256;
constexpr int H = 7168;
constexpr float NEG_INF = -1e9f;

constexpr size_t WT_BYTES     = (size_t)H * E * 4;        // 7,340,032
constexpr size_t LOGITS_BYTES = (size_t)T * E * 4;        // 8,388,608
constexpr size_t WS_NEEDED    = WT_BYTES + LOGITS_BYTES;  // 15,728,640

// ---------------- kernel 0: transpose W[E][H] -> Wt[H][E] ----------------
__global__ __launch_bounds__(256) void transposeW(const float* __restrict__ W,
                                                  float* __restrict__ Wt) {
  __shared__ float tile[32][33];
  const int bx = blockIdx.x;            // k tile: H/32 = 224
  const int by = blockIdx.y;            // e tile: E/32 = 8
  const int tx = threadIdx.x & 31;
  const int ty = threadIdx.x >> 5;      // 0..7
#pragma unroll
  for (int i = 0; i < 4; ++i)
    tile[ty + i * 8][tx] = W[(size_t)(by * 32 + ty + i * 8) * H + bx * 32 + tx];
  __syncthreads();
#pragma unroll
  for (int i = 0; i < 4; ++i)
    Wt[(size_t)(bx * 32 + ty + i * 8) * E + by * 32 + tx] = tile[tx][ty + i * 8];
}

// ---------------- kernel 1: logits GEMM (no LDS, W in SGPRs) ----------------
// grid 512 = 128 token-sets x 4 expert-quarters (x = e-quarter so neighbors
// share A rows through L2/L3). block 256 thr = 4 waves; wave = 64 tokens
// (lane = token) x 16 wave-uniform experts.
__global__ __launch_bounds__(256) void gemm_logits(const float* __restrict__ A,
                                                   const float* __restrict__ Wt,
                                                   float* __restrict__ logits) {
  const int lane = threadIdx.x & 63;
  const int wid  = __builtin_amdgcn_readfirstlane(threadIdx.x >> 6);  // 0..3
  const int m0   = (int)(blockIdx.x >> 2) * 64;
  const int eo   = (int)(blockIdx.x & 3) * 64 + wid * 16;  // uniform, 64B-aligned
  const int m    = m0 + lane;

  const float* __restrict__ arow = A + (size_t)m * H;

  float acc[16];
#pragma unroll
  for (int j = 0; j < 16; ++j) acc[j] = 0.f;

  float4 a = *(const float4*)&arow[0];
  for (int k4 = 0; k4 < H; k4 += 4) {
    float4 an;
    if (k4 + 4 < H) an = *(const float4*)&arow[k4 + 4];
#pragma unroll
    for (int kk = 0; kk < 4; ++kk) {
      const float* __restrict__ wp = Wt + (size_t)(k4 + kk) * E + eo;  // uniform addr
      const float av = (kk == 0) ? a.x : (kk == 1) ? a.y : (kk == 2) ? a.z : a.w;
#pragma unroll
      for (int j = 0; j < 16; ++j) acc[j] = fmaf(av, wp[j], acc[j]);
    }
    a = an;
  }

  float* lrow = logits + (size_t)m * E + eo;
#pragma unroll
  for (int j = 0; j < 4; ++j)
    *(float4*)&lrow[j * 4] = make_float4(acc[4 * j], acc[4 * j + 1], acc[4 * j + 2], acc[4 * j + 3]);
}

// ---------------- kernel 2: routing epilogue (verified in round 1) ----------------
__global__ __launch_bounds__(1024) void routing(const float* __restrict__ logits,
                                                const float* __restrict__ bias,
                                                float* __restrict__ out) {
  const int lane = threadIdx.x & 63;
  const int wid  = threadIdx.x >> 6;  // 0..15
  const int m0   = blockIdx.x * 32;
  const float4 b4 = ((const float4*)bias)[lane];

  for (int tk = 0; tk < 2; ++tk) {
    const int m = m0 + wid * 2 + tk;
    const float4 l4 = *(const float4*)&logits[(size_t)m * E + lane * 4];
    const float su0 = 1.f / (1.f + expf(-l4.x));
    const float su1 = 1.f / (1.f + expf(-l4.y));
    const float su2 = 1.f / (1.f + expf(-l4.z));
    const float su3 = 1.f / (1.f + expf(-l4.w));
    float sc0 = su0 + b4.x;
    float sc1 = su1 + b4.y;
    float sc2 = su2 + b4.z;
    float sc3 = su3 + b4.w;

    // per-lane top2 of 4 (biased scores)
    float t1, t2;
    {
      const float p1 = fmaxf(sc0, sc1), p2 = fminf(sc0, sc1);
      const float q1 = fmaxf(sc2, sc3), q2 = fminf(sc2, sc3);
      t1 = fmaxf(p1, q1);
      t2 = fmaxf(fminf(p1, q1), fmaxf(p2, q2));
    }
    // reduce top2 across the 8 lanes of this group
#pragma unroll
    for (int d = 1; d < 8; d <<= 1) {
      const float o1 = __shfl_xor(t1, d);
      const float o2 = __shfl_xor(t2, d);
      const float n1 = fmaxf(t1, o1);
      const float n2 = fmaxf(fminf(t1, o1), fmaxf(t2, o2));
      t1 = n1; t2 = n2;
    }
    const float gs = t1 + t2;

    // rank my group among all 8 (ties -> lower group index wins)
    const int gme = lane >> 3;
    int rank = 0;
#pragma unroll
    for (int g = 0; g < 8; ++g) {
      const float og = __shfl(gs, g * 8);
      rank += (og > gs) || (og == gs && g < gme);
    }
    const bool keep = (rank < 4);

    float mk0 = keep ? sc0 : NEG_INF;
    float mk1 = keep ? sc1 : NEG_INF;
    float mk2 = keep ? sc2 : NEG_INF;
    float mk3 = keep ? sc3 : NEG_INF;

    float wvals[8];
    int   widx[8];
    float wsum = 0.f;

#pragma unroll
    for (int j = 0; j < 8; ++j) {
      float bv = mk0; int bq = 0;
      if (mk1 > bv) { bv = mk1; bq = 1; }
      if (mk2 > bv) { bv = mk2; bq = 2; }
      if (mk3 > bv) { bv = mk3; bq = 3; }
      int bidx = lane * 4 + bq;
#pragma unroll
      for (int d = 1; d < 64; d <<= 1) {
        const float ov = __shfl_xor(bv, d);
        const int   oi = __shfl_xor(bidx, d);
        if (ov > bv || (ov == bv && oi < bidx)) { bv = ov; bidx = oi; }
      }
      const int ol = bidx >> 2;
      const int oq = bidx & 3;
      const float sv = (oq == 0) ? su0 : (oq == 1) ? su1 : (oq == 2) ? su2 : su3;
      const float wj = __shfl(sv, ol);
      if (lane == ol) {
        if (oq == 0) mk0 = -3.4e38f;
        else if (oq == 1) mk1 = -3.4e38f;
        else if (oq == 2) mk2 = -3.4e38f;
        else mk3 = -3.4e38f;
      }
      wsum += wj;
      wvals[j] = wj;
      widx[j]  = bidx;
    }

    if (lane == 0) {
      const float scale = 2.5f / (wsum + 1e-20f);
      const size_t row = (size_t)m * 8;
#pragma unroll
      for (int j = 0; j < 8; ++j) {
        out[row + j]                 = (float)widx[j];
        out[(size_t)T * 8 + row + j] = wvals[j] * scale;
      }
    }
  }
}

// ---------------- fallback: round-1 fused kernel (ws too small) ----------------
constexpr int BM  = 32;
constexpr int BK  = 32;
constexpr int NTH = 1024;
constexpr int PA  = 34;
constexpr int PW  = 260;

__global__ __launch_bounds__(NTH) void gate_fused(
    const float* __restrict__ A, const float* __restrict__ Wf,
    const float* __restrict__ bias, float* __restrict__ out) {
  __shared__ __align__(16) float sA[BK * PA];
  __shared__ __align__(16) float sW[BK * PW];
  const int tid = threadIdx.x;
  const int m0  = blockIdx.x * BM;
  const int m2 = tid & 15;
  const int eq = tid >> 4;
  const int wi  = tid * 2;
  const int we  = wi >> 3;
  const int wkq = wi & 7;
  const size_t wbase = (size_t)we * H + (size_t)wkq * 4;
  const int am  = tid >> 3;
  const int akq = tid & 7;
  const size_t abase = (size_t)(m0 + am) * H + (size_t)akq * 4;
  float4 rw0, rw1, ra;
  rw0 = *(const float4*)&Wf[wbase];
  rw1 = *(const float4*)&Wf[wbase + 4];
  if (tid < 256) ra = *(const float4*)&A[abase];
  float acc[2][4] = {{0.f,0.f,0.f,0.f},{0.f,0.f,0.f,0.f}};
  for (int k0 = 0; k0 < H; k0 += BK) {
    sW[(wkq*4+0)*PW+we]=rw0.x; sW[(wkq*4+1)*PW+we]=rw0.y;
    sW[(wkq*4+2)*PW+we]=rw0.z; sW[(wkq*4+3)*PW+we]=rw0.w;
    sW[(wkq*4+4)*PW+we]=rw1.x; sW[(wkq*4+5)*PW+we]=rw1.y;
    sW[(wkq*4+6)*PW+we]=rw1.z; sW[(wkq*4+7)*PW+we]=rw1.w;
    if (tid < 256) {
      sA[(akq*4+0)*PA+am]=ra.x; sA[(akq*4+1)*PA+am]=ra.y;
      sA[(akq*4+2)*PA+am]=ra.z; sA[(akq*4+3)*PA+am]=ra.w;
    }
    __syncthreads();
    if (k0 + BK < H) {
      rw0 = *(const float4*)&Wf[wbase + (size_t)(k0+BK)];
      rw1 = *(const float4*)&Wf[wbase + (size_t)(k0+BK) + 4];
      if (tid < 256) ra = *(const float4*)&A[abase + (size_t)(k0+BK)];
    }
#pragma unroll
    for (int k = 0; k < BK; ++k) {
      const float2 av = *(const float2*)&sA[k*PA + m2*2];
      const float4 wv = *(const float4*)&sW[k*PW + eq*4];
      acc[0][0]=fmaf(av.x,wv.x,acc[0][0]); acc[0][1]=fmaf(av.x,wv.y,acc[0][1]);
      acc[0][2]=fmaf(av.x,wv.z,acc[0][2]); acc[0][3]=fmaf(av.x,wv.w,acc[0][3]);
      acc[1][0]=fmaf(av.y,wv.x,acc[1][0]); acc[1][1]=fmaf(av.y,wv.y,acc[1][1]);
      acc[1][2]=fmaf(av.y,wv.z,acc[1][2]); acc[1][3]=fmaf(av.y,wv.w,acc[1][3]);
    }
    __syncthreads();
  }
#pragma unroll
  for (int tk = 0; tk < 2; ++tk) {
    const int m = 2*m2 + tk;
#pragma unroll
    for (int j = 0; j < 4; ++j)
      sW[m*PW + eq*4 + j] = 1.f/(1.f+expf(-acc[tk][j]));
  }
  __syncthreads();
  const int lane = tid & 63;
  const int wid  = tid >> 6;
  const float4 b4 = ((const float4*)bias)[lane];
  for (int tk = 0; tk < 2; ++tk) {
    const int m = wid*2 + tk;
    const float4 s4 = *(const float4*)&sW[m*PW + lane*4];
    const float su0=s4.x, su1=s4.y, su2=s4.z, su3=s4.w;
    float sc0=s4.x+b4.x, sc1=s4.y+b4.y, sc2=s4.z+b4.z, sc3=s4.w+b4.w;
    float t1, t2;
    {
      const float p1=fmaxf(sc0,sc1), p2=fminf(sc0,sc1);
      const float q1=fmaxf(sc2,sc3), q2=fminf(sc2,sc3);
      t1=fmaxf(p1,q1); t2=fmaxf(fminf(p1,q1),fmaxf(p2,q2));
    }
#pragma unroll
    for (int d = 1; d < 8; d <<= 1) {
      const float o1=__shfl_xor(t1,d), o2=__shfl_xor(t2,d);
      const float n1=fmaxf(t1,o1), n2=fmaxf(fminf(t1,o1),fmaxf(t2,o2));
      t1=n1; t2=n2;
    }
    const float gs = t1 + t2;
    const int gme = lane >> 3;
    int rank = 0;
#pragma unroll
    for (int g = 0; g < 8; ++g) {
      const float og = __shfl(gs, g*8);
      rank += (og > gs) || (og == gs && g < gme);
    }
    const bool keep = (rank < 4);
    float mk0=keep?sc0:NEG_INF, mk1=keep?sc1:NEG_INF, mk2=keep?sc2:NEG_INF, mk3=keep?sc3:NEG_INF;
    float wvals[8]; int widx[8]; float wsum = 0.f;
#pragma unroll
    for (int j = 0; j < 8; ++j) {
      float bv=mk0; int bq=0;
      if (mk1>bv){bv=mk1;bq=1;} if (mk2>bv){bv=mk2;bq=2;} if (mk3>bv){bv=mk3;bq=3;}
      int bidx = lane*4 + bq;
#pragma unroll
      for (int d = 1; d < 64; d <<= 1) {
        const float ov=__shfl_xor(bv,d); const int oi=__shfl_xor(bidx,d);
        if (ov>bv || (ov==bv && oi<bidx)) { bv=ov; bidx=oi; }
      }
      const int ol=bidx>>2, oq=bidx&3;
      const float sv=(oq==0)?su0:(oq==1)?su1:(oq==2)?su2:su3;
      const float wj=__shfl(sv,ol);
      if (lane==ol) {
        if (oq==0) mk0=-3.4e38f; else if (oq==1) mk1=-3.4e38f;
        else if (oq==2) mk2=-3.4e38f; else mk3=-3.4e38f;
      }
      wsum+=wj; wvals[j]=wj; widx[j]=bidx;
    }
    if (lane==0) {
      const float scale = 2.5f/(wsum+1e-20f);
      const size_t row = (size_t)(m0+m)*8;
#pragma unroll
      for (int j = 0; j < 8; ++j) {
        out[row+j]=(float)widx[j]; out[(size_t)T*8+row+j]=wvals[j]*scale;
      }
    }
  }
}

}  // namespace

extern "C" void kernel_launch(void* const* d_in, const int* in_sizes, int n_in,
                              void* d_out, int out_size, void* d_ws, size_t ws_size,
                              hipStream_t stream) {
  const float* A    = (const float*)d_in[0];
  const float* W    = (const float*)d_in[1];
  const float* bias = (const float*)d_in[2];
  float* out = (float*)d_out;

  if (ws_size >= WS_NEEDED) {
    float* Wt     = (float*)d_ws;
    float* logits = (float*)((char*)d_ws + WT_BYTES);
    hipLaunchKernelGGL(transposeW, dim3(H / 32, E / 32), dim3(256), 0, stream, W, Wt);
    hipLaunchKernelGGL(gemm_logits, dim3(512), dim3(256), 0, stream, A, Wt, logits);
    hipLaunchKernelGGL(routing, dim3(T / 32), dim3(1024), 0, stream, logits, bias, out);
  } else {
    hipLaunchKernelGGL(gate_fused, dim3(T / BM), dim3(NTH), 0, stream, A, W, bias, out);
  }
}

// Round 4
// 866.477 us; speedup vs baseline: 1.0806x; 1.0806x over previous
//
#include <hip/hip_runtime.h>
#include <math.h>

namespace {

constexpr int T = 8192;
constexpr int E = 256;
constexpr int H = 7168;
constexpr float NEG_INF = -1e9f;

constexpr size_t WT_BYTES  = (size_t)H * E * 4;   // 7,340,032
constexpr size_t LOG_BYTES = (size_t)T * E * 4;   // 8,388,608
constexpr size_t WS_KS4    = WT_BYTES + 4 * LOG_BYTES;  // 40,894,464
constexpr size_t WS_KS1    = WT_BYTES + 1 * LOG_BYTES;  // 15,728,640

// ---------------- kernel 0: transpose W[E][H] -> Wt[H][E] ----------------
__global__ __launch_bounds__(256) void transposeW(const float* __restrict__ W,
                                                  float* __restrict__ Wt) {
  __shared__ float tile[32][33];
  const int bx = blockIdx.x;            // k tile: H/32 = 224
  const int by = blockIdx.y;            // e tile: E/32 = 8
  const int tx = threadIdx.x & 31;
  const int ty = threadIdx.x >> 5;      // 0..7
#pragma unroll
  for (int i = 0; i < 4; ++i)
    tile[ty + i * 8][tx] = W[(size_t)(by * 32 + ty + i * 8) * H + bx * 32 + tx];
  __syncthreads();
#pragma unroll
  for (int i = 0; i < 4; ++i)
    Wt[(size_t)(bx * 32 + ty + i * 8) * E + by * 32 + tx] = tile[tx][ty + i * 8];
}

// ---------------- kernel 1: partial-logits GEMM, K-split across gridDim.y ----
// wave = 64 tokens (lane = token) x 16 wave-uniform experts over H/ksplit.
// W values ride in SGPRs (s_load), A is per-lane float4; no LDS at all.
__global__ __launch_bounds__(256) void gemm_ks(const float* __restrict__ A,
                                               const float* __restrict__ Wt,
                                               float* __restrict__ part) {
  const int lane = threadIdx.x & 63;
  const int wid  = __builtin_amdgcn_readfirstlane(threadIdx.x >> 6);  // 0..3
  const int m    = (int)blockIdx.z * 64 + lane;
  const int eo   = (int)blockIdx.x * 64 + wid * 16;   // uniform, 64B-aligned
  const int klen = H / (int)gridDim.y;                // uniform
  const int kbeg = (int)blockIdx.y * klen;

  const float* __restrict__ arow = A + (size_t)m * H + kbeg;
  const float* __restrict__ wb   = Wt + (size_t)kbeg * E + eo;

  float acc[16];
#pragma unroll
  for (int j = 0; j < 16; ++j) acc[j] = 0.f;

  float4 a = *(const float4*)&arow[0];
  int k4 = 0;
  for (; k4 + 4 < klen; k4 += 4) {
    const float4 an = *(const float4*)&arow[k4 + 4];   // prefetch next chunk
#pragma unroll
    for (int kk = 0; kk < 4; ++kk) {
      const float* __restrict__ wp = wb + (size_t)(k4 + kk) * E;  // uniform addr
      const float av = (kk == 0) ? a.x : (kk == 1) ? a.y : (kk == 2) ? a.z : a.w;
#pragma unroll
      for (int j = 0; j < 16; ++j) acc[j] = fmaf(av, wp[j], acc[j]);
    }
    a = an;
  }
  // epilogue chunk (no prefetch)
#pragma unroll
  for (int kk = 0; kk < 4; ++kk) {
    const float* __restrict__ wp = wb + (size_t)(k4 + kk) * E;
    const float av = (kk == 0) ? a.x : (kk == 1) ? a.y : (kk == 2) ? a.z : a.w;
#pragma unroll
    for (int j = 0; j < 16; ++j) acc[j] = fmaf(av, wp[j], acc[j]);
  }

  float* pr = part + (size_t)blockIdx.y * (size_t)T * E + (size_t)m * E + eo;
#pragma unroll
  for (int j = 0; j < 4; ++j)
    *(float4*)&pr[j * 4] =
        make_float4(acc[4 * j], acc[4 * j + 1], acc[4 * j + 2], acc[4 * j + 3]);
}

// ---------------- kernel 2: reduce partials + routing epilogue ----------------
__global__ __launch_bounds__(1024) void routing(const float* __restrict__ part,
                                                const float* __restrict__ bias,
                                                float* __restrict__ out, int nparts) {
  const int lane = threadIdx.x & 63;
  const int wid  = threadIdx.x >> 6;  // 0..15
  const int m0   = blockIdx.x * 32;
  const float4 b4 = ((const float4*)bias)[lane];

  for (int tk = 0; tk < 2; ++tk) {
    const int m = m0 + wid * 2 + tk;
    const size_t off = (size_t)m * E + lane * 4;
    float4 l4 = *(const float4*)&part[off];
    for (int s = 1; s < nparts; ++s) {
      const float4 q = *(const float4*)&part[(size_t)s * T * E + off];
      l4.x += q.x; l4.y += q.y; l4.z += q.z; l4.w += q.w;
    }
    const float su0 = 1.f / (1.f + expf(-l4.x));
    const float su1 = 1.f / (1.f + expf(-l4.y));
    const float su2 = 1.f / (1.f + expf(-l4.z));
    const float su3 = 1.f / (1.f + expf(-l4.w));
    float sc0 = su0 + b4.x;
    float sc1 = su1 + b4.y;
    float sc2 = su2 + b4.z;
    float sc3 = su3 + b4.w;

    // per-lane top2 of 4 (biased scores)
    float t1, t2;
    {
      const float p1 = fmaxf(sc0, sc1), p2 = fminf(sc0, sc1);
      const float q1 = fmaxf(sc2, sc3), q2 = fminf(sc2, sc3);
      t1 = fmaxf(p1, q1);
      t2 = fmaxf(fminf(p1, q1), fmaxf(p2, q2));
    }
    // reduce top2 across the 8 lanes of this group
#pragma unroll
    for (int d = 1; d < 8; d <<= 1) {
      const float o1 = __shfl_xor(t1, d);
      const float o2 = __shfl_xor(t2, d);
      const float n1 = fmaxf(t1, o1);
      const float n2 = fmaxf(fminf(t1, o1), fmaxf(t2, o2));
      t1 = n1; t2 = n2;
    }
    const float gs = t1 + t2;

    // rank my group among all 8 (ties -> lower group index wins)
    const int gme = lane >> 3;
    int rank = 0;
#pragma unroll
    for (int g = 0; g < 8; ++g) {
      const float og = __shfl(gs, g * 8);
      rank += (og > gs) || (og == gs && g < gme);
    }
    const bool keep = (rank < 4);

    float mk0 = keep ? sc0 : NEG_INF;
    float mk1 = keep ? sc1 : NEG_INF;
    float mk2 = keep ? sc2 : NEG_INF;
    float mk3 = keep ? sc3 : NEG_INF;

    float wvals[8];
    int   widx[8];
    float wsum = 0.f;

#pragma unroll
    for (int j = 0; j < 8; ++j) {
      float bv = mk0; int bq = 0;
      if (mk1 > bv) { bv = mk1; bq = 1; }
      if (mk2 > bv) { bv = mk2; bq = 2; }
      if (mk3 > bv) { bv = mk3; bq = 3; }
      int bidx = lane * 4 + bq;
#pragma unroll
      for (int d = 1; d < 64; d <<= 1) {
        const float ov = __shfl_xor(bv, d);
        const int   oi = __shfl_xor(bidx, d);
        if (ov > bv || (ov == bv && oi < bidx)) { bv = ov; bidx = oi; }
      }
      const int ol = bidx >> 2;
      const int oq = bidx & 3;
      const float sv = (oq == 0) ? su0 : (oq == 1) ? su1 : (oq == 2) ? su2 : su3;
      const float wj = __shfl(sv, ol);
      if (lane == ol) {
        if (oq == 0) mk0 = -3.4e38f;
        else if (oq == 1) mk1 = -3.4e38f;
        else if (oq == 2) mk2 = -3.4e38f;
        else mk3 = -3.4e38f;
      }
      wsum += wj;
      wvals[j] = wj;
      widx[j]  = bidx;
    }

    if (lane == 0) {
      const float scale = 2.5f / (wsum + 1e-20f);
      const size_t row = (size_t)m * 8;
#pragma unroll
      for (int j = 0; j < 8; ++j) {
        out[row + j]                 = (float)widx[j];
        out[(size_t)T * 8 + row + j] = wvals[j] * scale;
      }
    }
  }
}

// ---------------- fallback: round-1 fused kernel (tiny ws) ----------------
constexpr int BM  = 32;
constexpr int BK  = 32;
constexpr int NTH = 1024;
constexpr int PA  = 34;
constexpr int PW  = 260;

__global__ __launch_bounds__(NTH) void gate_fused(
    const float* __restrict__ A, const float* __restrict__ Wf,
    const float* __restrict__ bias, float* __restrict__ out) {
  __shared__ __align__(16) float sA[BK * PA];
  __shared__ __align__(16) float sW[BK * PW];
  const int tid = threadIdx.x;
  const int m0  = blockIdx.x * BM;
  const int m2 = tid & 15;
  const int eq = tid >> 4;
  const int wi  = tid * 2;
  const int we  = wi >> 3;
  const int wkq = wi & 7;
  const size_t wbase = (size_t)we * H + (size_t)wkq * 4;
  const int am  = tid >> 3;
  const int akq = tid & 7;
  const size_t abase = (size_t)(m0 + am) * H + (size_t)akq * 4;
  float4 rw0, rw1, ra;
  rw0 = *(const float4*)&Wf[wbase];
  rw1 = *(const float4*)&Wf[wbase + 4];
  if (tid < 256) ra = *(const float4*)&A[abase];
  float acc[2][4] = {{0.f,0.f,0.f,0.f},{0.f,0.f,0.f,0.f}};
  for (int k0 = 0; k0 < H; k0 += BK) {
    sW[(wkq*4+0)*PW+we]=rw0.x; sW[(wkq*4+1)*PW+we]=rw0.y;
    sW[(wkq*4+2)*PW+we]=rw0.z; sW[(wkq*4+3)*PW+we]=rw0.w;
    sW[(wkq*4+4)*PW+we]=rw1.x; sW[(wkq*4+5)*PW+we]=rw1.y;
    sW[(wkq*4+6)*PW+we]=rw1.z; sW[(wkq*4+7)*PW+we]=rw1.w;
    if (tid < 256) {
      sA[(akq*4+0)*PA+am]=ra.x; sA[(akq*4+1)*PA+am]=ra.y;
      sA[(akq*4+2)*PA+am]=ra.z; sA[(akq*4+3)*PA+am]=ra.w;
    }
    __syncthreads();
    if (k0 + BK < H) {
      rw0 = *(const float4*)&Wf[wbase + (size_t)(k0+BK)];
      rw1 = *(const float4*)&Wf[wbase + (size_t)(k0+BK) + 4];
      if (tid < 256) ra = *(const float4*)&A[abase + (size_t)(k0+BK)];
    }
#pragma unroll
    for (int k = 0; k < BK; ++k) {
      const float2 av = *(const float2*)&sA[k*PA + m2*2];
      const float4 wv = *(const float4*)&sW[k*PW + eq*4];
      acc[0][0]=fmaf(av.x,wv.x,acc[0][0]); acc[0][1]=fmaf(av.x,wv.y,acc[0][1]);
      acc[0][2]=fmaf(av.x,wv.z,acc[0][2]); acc[0][3]=fmaf(av.x,wv.w,acc[0][3]);
      acc[1][0]=fmaf(av.y,wv.x,acc[1][0]); acc[1][1]=fmaf(av.y,wv.y,acc[1][1]);
      acc[1][2]=fmaf(av.y,wv.z,acc[1][2]); acc[1][3]=fmaf(av.y,wv.w,acc[1][3]);
    }
    __syncthreads();
  }
#pragma unroll
  for (int tk = 0; tk < 2; ++tk) {
    const int m = 2*m2 + tk;
#pragma unroll
    for (int j = 0; j < 4; ++j)
      sW[m*PW + eq*4 + j] = 1.f/(1.f+expf(-acc[tk][j]));
  }
  __syncthreads();
  const int lane = tid & 63;
  const int wid  = tid >> 6;
  const float4 b4 = ((const float4*)bias)[lane];
  for (int tk = 0; tk < 2; ++tk) {
    const int m = wid*2 + tk;
    const float4 s4 = *(const float4*)&sW[m*PW + lane*4];
    const float su0=s4.x, su1=s4.y, su2=s4.z, su3=s4.w;
    float sc0=s4.x+b4.x, sc1=s4.y+b4.y, sc2=s4.z+b4.z, sc3=s4.w+b4.w;
    float t1, t2;
    {
      const float p1=fmaxf(sc0,sc1), p2=fminf(sc0,sc1);
      const float q1=fmaxf(sc2,sc3), q2=fminf(sc2,sc3);
      t1=fmaxf(p1,q1); t2=fmaxf(fminf(p1,q1),fmaxf(p2,q2));
    }
#pragma unroll
    for (int d = 1; d < 8; d <<= 1) {
      const float o1=__shfl_xor(t1,d), o2=__shfl_xor(t2,d);
      const float n1=fmaxf(t1,o1), n2=fmaxf(fminf(t1,o1),fmaxf(t2,o2));
      t1=n1; t2=n2;
    }
    const float gs = t1 + t2;
    const int gme = lane >> 3;
    int rank = 0;
#pragma unroll
    for (int g = 0; g < 8; ++g) {
      const float og = __shfl(gs, g*8);
      rank += (og > gs) || (og == gs && g < gme);
    }
    const bool keep = (rank < 4);
    float mk0=keep?sc0:NEG_INF, mk1=keep?sc1:NEG_INF, mk2=keep?sc2:NEG_INF, mk3=keep?sc3:NEG_INF;
    float wvals[8]; int widx[8]; float wsum = 0.f;
#pragma unroll
    for (int j = 0; j < 8; ++j) {
      float bv=mk0; int bq=0;
      if (mk1>bv){bv=mk1;bq=1;} if (mk2>bv){bv=mk2;bq=2;} if (mk3>bv){bv=mk3;bq=3;}
      int bidx = lane*4 + bq;
#pragma unroll
      for (int d = 1; d < 64; d <<= 1) {
        const float ov=__shfl_xor(bv,d); const int oi=__shfl_xor(bidx,d);
        if (ov>bv || (ov==bv && oi<bidx)) { bv=ov; bidx=oi; }
      }
      const int ol=bidx>>2, oq=bidx&3;
      const float sv=(oq==0)?su0:(oq==1)?su1:(oq==2)?su2:su3;
      const float wj=__shfl(sv,ol);
      if (lane==ol) {
        if (oq==0) mk0=-3.4e38f; else if (oq==1) mk1=-3.4e38f;
        else if (oq==2) mk2=-3.4e38f; else mk3=-3.4e38f;
      }
      wsum+=wj; wvals[j]=wj; widx[j]=bidx;
    }
    if (lane==0) {
      const float scale = 2.5f/(wsum+1e-20f);
      const size_t row = (size_t)(m0+m)*8;
#pragma unroll
      for (int j = 0; j < 8; ++j) {
        out[row+j]=(float)widx[j]; out[(size_t)T*8+row+j]=wvals[j]*scale;
      }
    }
  }
}

}  // namespace

extern "C" void kernel_launch(void* const* d_in, const int* in_sizes, int n_in,
                              void* d_out, int out_size, void* d_ws, size_t ws_size,
                              hipStream_t stream) {
  const float* A    = (const float*)d_in[0];
  const float* W    = (const float*)d_in[1];
  const float* bias = (const float*)d_in[2];
  float* out = (float*)d_out;

  const int nks = (ws_size >= WS_KS4) ? 4 : (ws_size >= WS_KS1) ? 1 : 0;
  if (nks > 0) {
    float* Wt   = (float*)d_ws;
    float* part = (float*)((char*)d_ws + WT_BYTES);
    hipLaunchKernelGGL(transposeW, dim3(H / 32, E / 32), dim3(256), 0, stream, W, Wt);
    hipLaunchKernelGGL(gemm_ks, dim3(4, nks, 128), dim3(256), 0, stream, A, Wt, part);
    hipLaunchKernelGGL(routing, dim3(T / 32), dim3(1024), 0, stream, part, bias, out, nks);
  } else {
    hipLaunchKernelGGL(gate_fused, dim3(T / BM), dim3(NTH), 0, stream, A, W, bias, out);
  }
}

// Round 6
// 422.870 us; speedup vs baseline: 2.2142x; 2.0490x over previous
//
#include <hip/hip_runtime.h>
#include <math.h>

namespace {

constexpr int T = 8192;
constexpr int E = 256;
constexpr int H = 7168;
constexpr float NEG_INF = -1e9f;

// ---------------- f16x2-split MFMA path geometry ----------------
constexpr int KS   = 2;           // k-splits
constexpr int KLEN = H / KS;      // 3584
constexpr int NC   = KLEN / 32;   // 112 chunks of 32 k
// W-tile LDS/global image: per chunk: 2 planes x 128 experts x 80B rows
constexpr int CHUNK_BYTES = 2 * 128 * 80;  // 20480
constexpr size_t WSPLIT_BYTES = (size_t)KS * 2 /*e-halves*/ * NC * CHUNK_BYTES; // 9,175,040
constexpr size_t PART_BYTES   = (size_t)KS * T * E * 4;                          // 16,777,216
constexpr size_t WS_NEW       = WSPLIT_BYTES + PART_BYTES;                       // 25,952,256

typedef _Float16 half4 __attribute__((ext_vector_type(4)));
typedef _Float16 half8 __attribute__((ext_vector_type(8)));
typedef float f32x4 __attribute__((ext_vector_type(4)));

// legacy scalar-path ws layout (fallback only)
constexpr size_t WT_BYTES  = (size_t)H * E * 4;
constexpr size_t LOG_BYTES = (size_t)T * E * 4;
constexpr size_t WS_KS4    = WT_BYTES + 4 * LOG_BYTES;
constexpr size_t WS_KS1    = WT_BYTES + 1 * LOG_BYTES;

// ---------------- kernel: split W[E][H] fp32 -> f16 hi/lo tile images ----------
// hi = f16(16*w), lo = f16(4096*(w - hi/16)); scales keep planes f16-normal.
// Image layout: slot(q, eh, c) of 20480B = [pl 2][el 128][80B row: 32 k f16 + pad]
__global__ __launch_bounds__(256) void wsplit(const float* __restrict__ W,
                                              char* __restrict__ wt) {
  const int tid = blockIdx.x * 256 + threadIdx.x;   // 256*1792 threads
  const int e  = tid / 1792;                        // expert row
  const int k4 = tid % 1792;                        // float4 index in row
  const int k  = k4 * 4;
  const int q  = k / KLEN;
  const int kr = k - q * KLEN;
  const int c  = kr >> 5;
  const int kk = kr & 31;
  const int eh = e >> 7, el = e & 127;

  const float4 w4 = *(const float4*)&W[(size_t)e * H + k];
  half4 hv, lv;
  {
    float x;
    x = w4.x; hv[0] = (_Float16)(x * 16.f); lv[0] = (_Float16)((x - (float)hv[0] * 0.0625f) * 4096.f);
    x = w4.y; hv[1] = (_Float16)(x * 16.f); lv[1] = (_Float16)((x - (float)hv[1] * 0.0625f) * 4096.f);
    x = w4.z; hv[2] = (_Float16)(x * 16.f); lv[2] = (_Float16)((x - (float)hv[2] * 0.0625f) * 4096.f);
    x = w4.w; hv[3] = (_Float16)(x * 16.f); lv[3] = (_Float16)((x - (float)hv[3] * 0.0625f) * 4096.f);
  }
  char* base = wt + ((size_t)((q * 2 + eh) * NC + c)) * CHUNK_BYTES + el * 80 + kk * 2;
  *(half4*)(base)         = hv;   // plane 0 (hi)
  *(half4*)(base + 10240) = lv;   // plane 1 (lo)
}

// ---------------- kernel: logits GEMM via mfma_f32_16x16x32_f16 ----------------
// grid(eh=2, mb=128, q=2); 256 thr = 4 waves; wave-tile 64m x 32e (mt=4, et=2).
// C[m][e] = sum_k A[m][k] * W[e][k]:  arg0 = A-frag (row=m), arg1 = W-frag (row=e).
// Frag layout (16x16x32): lane l: free-idx = l&15, k = (l>>4)*8 + j (8 contiguous f16).
// C/D: row = (l>>4)*4 + j, col = l&15  [guide §3, m89-verified].
__global__ __launch_bounds__(256, 2) void gemm_f16(const float* __restrict__ A,
                                                   const char* __restrict__ wt,
                                                   float* __restrict__ part) {
  __shared__ char smem[30720];  // A': [2pl][64 m][80B] @0 (stride 5120); W: [2pl][128 e][80B] @10240 (stride 10240)
  const int tid  = threadIdx.x;
  const int lane = tid & 63;
  const int w    = tid >> 6;      // wave 0..3
  const int l4   = lane & 15;
  const int g    = lane >> 4;

  const int eh = blockIdx.x;
  const int m0 = (int)blockIdx.y * 64;
  const int q  = blockIdx.z;
  const int e0 = eh * 128;

  const char* wchunk0 = wt + ((size_t)(q * 2 + eh) * NC) * CHUNK_BYTES;

  // A staging: thread t handles rows (t>>3) and (t>>3)+32, k-quad t&7
  const int ar = tid >> 3;
  const int kq = tid & 7;
  const float* aptr0 = A + (size_t)(m0 + ar) * H + (size_t)q * KLEN + kq * 4;
  const float* aptr1 = A + (size_t)(m0 + ar + 32) * H + (size_t)q * KLEN + kq * 4;

  f32x4 acc_hh[4][2], acc_x[4][2];
#pragma unroll
  for (int i = 0; i < 4; ++i)
#pragma unroll
    for (int j = 0; j < 2; ++j) {
      acc_hh[i][j] = (f32x4)0.f;
      acc_x[i][j]  = (f32x4)0.f;
    }

  float4 af0 = *(const float4*)aptr0;
  float4 af1 = *(const float4*)aptr1;

  for (int c = 0; c < NC; ++c) {
    __syncthreads();  // previous compute done; LDS free

    // ---- split + write A' (hi unscaled, lo = 256*residual) ----
    {
      half4 hv, lv;
      float x;
      x = af0.x; hv[0] = (_Float16)x; lv[0] = (_Float16)((x - (float)hv[0]) * 256.f);
      x = af0.y; hv[1] = (_Float16)x; lv[1] = (_Float16)((x - (float)hv[1]) * 256.f);
      x = af0.z; hv[2] = (_Float16)x; lv[2] = (_Float16)((x - (float)hv[2]) * 256.f);
      x = af0.w; hv[3] = (_Float16)x; lv[3] = (_Float16)((x - (float)hv[3]) * 256.f);
      *(half4*)&smem[ar * 80 + kq * 8]        = hv;
      *(half4*)&smem[5120 + ar * 80 + kq * 8] = lv;
      x = af1.x; hv[0] = (_Float16)x; lv[0] = (_Float16)((x - (float)hv[0]) * 256.f);
      x = af1.y; hv[1] = (_Float16)x; lv[1] = (_Float16)((x - (float)hv[1]) * 256.f);
      x = af1.z; hv[2] = (_Float16)x; lv[2] = (_Float16)((x - (float)hv[2]) * 256.f);
      x = af1.w; hv[3] = (_Float16)x; lv[3] = (_Float16)((x - (float)hv[3]) * 256.f);
      *(half4*)&smem[(ar + 32) * 80 + kq * 8]        = hv;
      *(half4*)&smem[5120 + (ar + 32) * 80 + kq * 8] = lv;
    }

    // ---- stage W chunk image (20480B): 5 x (global float4 -> ds_write_b128) ----
    {
      const float4* wsrc = (const float4*)(wchunk0 + (size_t)c * CHUNK_BYTES);
#pragma unroll
      for (int r = 0; r < 5; ++r)
        *(float4*)&smem[10240 + (r * 256 + tid) * 16] = wsrc[r * 256 + tid];
    }

    // ---- prefetch next A chunk ----
    if (c + 1 < NC) {
      af0 = *(const float4*)(aptr0 + (c + 1) * 32);
      af1 = *(const float4*)(aptr1 + (c + 1) * 32);
    }

    __syncthreads();  // staging visible

    // ---- fragments + MFMA ----
    half8 ah[4], al[4], bh[2], bl[2];
#pragma unroll
    for (int mt = 0; mt < 4; ++mt) {
      const int ab = (mt * 16 + l4) * 80 + g * 16;
      ah[mt] = *(const half8*)&smem[ab];
      al[mt] = *(const half8*)&smem[5120 + ab];
    }
#pragma unroll
    for (int et = 0; et < 2; ++et) {
      const int bb = 10240 + (w * 32 + et * 16 + l4) * 80 + g * 16;
      bh[et] = *(const half8*)&smem[bb];
      bl[et] = *(const half8*)&smem[bb + 10240];
    }
#pragma unroll
    for (int mt = 0; mt < 4; ++mt)
#pragma unroll
      for (int et = 0; et < 2; ++et) {
        acc_hh[mt][et] = __builtin_amdgcn_mfma_f32_16x16x32_f16(ah[mt], bh[et], acc_hh[mt][et], 0, 0, 0);
        acc_x[mt][et]  = __builtin_amdgcn_mfma_f32_16x16x32_f16(ah[mt], bl[et], acc_x[mt][et], 0, 0, 0);
        acc_x[mt][et]  = __builtin_amdgcn_mfma_f32_16x16x32_f16(al[mt], bh[et], acc_x[mt][et], 0, 0, 0);
      }
  }

  // ---- epilogue: combine scales, write fp32 partial logits ----
  float* pq = part + (size_t)q * T * E;
#pragma unroll
  for (int mt = 0; mt < 4; ++mt)
#pragma unroll
    for (int et = 0; et < 2; ++et) {
      const int ebase = e0 + w * 32 + et * 16 + l4;
      const int mbase = m0 + mt * 16 + g * 4;
      const f32x4 vh = acc_hh[mt][et];
      const f32x4 vx = acc_x[mt][et];
#pragma unroll
      for (int j = 0; j < 4; ++j)
        pq[(size_t)(mbase + j) * E + ebase] = vh[j] * 0.0625f + vx[j] * (1.f / 4096.f);
    }
}

// ---------------- kernel: reduce partials + routing epilogue (r1/r4-verified) ----
__global__ __launch_bounds__(1024) void routing(const float* __restrict__ part,
                                                const float* __restrict__ bias,
                                                float* __restrict__ out, int nparts) {
  const int lane = threadIdx.x & 63;
  const int wid  = threadIdx.x >> 6;
  const int m0   = blockIdx.x * 32;
  const float4 b4 = ((const float4*)bias)[lane];

  for (int tk = 0; tk < 2; ++tk) {
    const int m = m0 + wid * 2 + tk;
    const size_t off = (size_t)m * E + lane * 4;
    float4 l4 = *(const float4*)&part[off];
    for (int s = 1; s < nparts; ++s) {
      const float4 qv = *(const float4*)&part[(size_t)s * T * E + off];
      l4.x += qv.x; l4.y += qv.y; l4.z += qv.z; l4.w += qv.w;
    }
    const float su0 = 1.f / (1.f + expf(-l4.x));
    const float su1 = 1.f / (1.f + expf(-l4.y));
    const float su2 = 1.f / (1.f + expf(-l4.z));
    const float su3 = 1.f / (1.f + expf(-l4.w));
    float sc0 = su0 + b4.x;
    float sc1 = su1 + b4.y;
    float sc2 = su2 + b4.z;
    float sc3 = su3 + b4.w;

    float t1, t2;
    {
      const float p1 = fmaxf(sc0, sc1), p2 = fminf(sc0, sc1);
      const float q1 = fmaxf(sc2, sc3), q2 = fminf(sc2, sc3);
      t1 = fmaxf(p1, q1);
      t2 = fmaxf(fminf(p1, q1), fmaxf(p2, q2));
    }
#pragma unroll
    for (int d = 1; d < 8; d <<= 1) {
      const float o1 = __shfl_xor(t1, d);
      const float o2 = __shfl_xor(t2, d);
      const float n1 = fmaxf(t1, o1);
      const float n2 = fmaxf(fminf(t1, o1), fmaxf(t2, o2));
      t1 = n1; t2 = n2;
    }
    const float gs = t1 + t2;

    const int gme = lane >> 3;
    int rank = 0;
#pragma unroll
    for (int gi = 0; gi < 8; ++gi) {
      const float og = __shfl(gs, gi * 8);
      rank += (og > gs) || (og == gs && gi < gme);
    }
    const bool keep = (rank < 4);

    float mk0 = keep ? sc0 : NEG_INF;
    float mk1 = keep ? sc1 : NEG_INF;
    float mk2 = keep ? sc2 : NEG_INF;
    float mk3 = keep ? sc3 : NEG_INF;

    float wvals[8];
    int   widx[8];
    float wsum = 0.f;

#pragma unroll
    for (int j = 0; j < 8; ++j) {
      float bv = mk0; int bq = 0;
      if (mk1 > bv) { bv = mk1; bq = 1; }
      if (mk2 > bv) { bv = mk2; bq = 2; }
      if (mk3 > bv) { bv = mk3; bq = 3; }
      int bidx = lane * 4 + bq;
#pragma unroll
      for (int d = 1; d < 64; d <<= 1) {
        const float ov = __shfl_xor(bv, d);
        const int   oi = __shfl_xor(bidx, d);
        if (ov > bv || (ov == bv && oi < bidx)) { bv = ov; bidx = oi; }
      }
      const int ol = bidx >> 2;
      const int oq = bidx & 3;
      const float sv = (oq == 0) ? su0 : (oq == 1) ? su1 : (oq == 2) ? su2 : su3;
      const float wj = __shfl(sv, ol);
      if (lane == ol) {
        if (oq == 0) mk0 = -3.4e38f;
        else if (oq == 1) mk1 = -3.4e38f;
        else if (oq == 2) mk2 = -3.4e38f;
        else mk3 = -3.4e38f;
      }
      wsum += wj;
      wvals[j] = wj;
      widx[j]  = bidx;
    }

    if (lane == 0) {
      const float scale = 2.5f / (wsum + 1e-20f);
      const size_t row = (size_t)m * 8;
#pragma unroll
      for (int j = 0; j < 8; ++j) {
        out[row + j]                 = (float)widx[j];
        out[(size_t)T * 8 + row + j] = wvals[j] * scale;
      }
    }
  }
}

// ---------------- fallbacks (scalar path; only if ws is small) ----------------
__global__ __launch_bounds__(256) void transposeW(const float* __restrict__ W,
                                                  float* __restrict__ Wt) {
  __shared__ float tile[32][33];
  const int bx = blockIdx.x, by = blockIdx.y;
  const int tx = threadIdx.x & 31, ty = threadIdx.x >> 5;
#pragma unroll
  for (int i = 0; i < 4; ++i)
    tile[ty + i * 8][tx] = W[(size_t)(by * 32 + ty + i * 8) * H + bx * 32 + tx];
  __syncthreads();
#pragma unroll
  for (int i = 0; i < 4; ++i)
    Wt[(size_t)(bx * 32 + ty + i * 8) * E + by * 32 + tx] = tile[tx][ty + i * 8];
}

__global__ __launch_bounds__(256) void gemm_ks(const float* __restrict__ A,
                                               const float* __restrict__ Wt,
                                               float* __restrict__ part) {
  const int lane = threadIdx.x & 63;
  const int wid  = __builtin_amdgcn_readfirstlane(threadIdx.x >> 6);
  const int m    = (int)blockIdx.z * 64 + lane;
  const int eo   = (int)blockIdx.x * 64 + wid * 16;
  const int klen = H / (int)gridDim.y;
  const int kbeg = (int)blockIdx.y * klen;
  const float* __restrict__ arow = A + (size_t)m * H + kbeg;
  const float* __restrict__ wb   = Wt + (size_t)kbeg * E + eo;
  float acc[16];
#pragma unroll
  for (int j = 0; j < 16; ++j) acc[j] = 0.f;
  float4 a = *(const float4*)&arow[0];
  int k4 = 0;
  for (; k4 + 4 < klen; k4 += 4) {
    const float4 an = *(const float4*)&arow[k4 + 4];
#pragma unroll
    for (int kk = 0; kk < 4; ++kk) {
      const float* __restrict__ wp = wb + (size_t)(k4 + kk) * E;
      const float av = (kk == 0) ? a.x : (kk == 1) ? a.y : (kk == 2) ? a.z : a.w;
#pragma unroll
      for (int j = 0; j < 16; ++j) acc[j] = fmaf(av, wp[j], acc[j]);
    }
    a = an;
  }
#pragma unroll
  for (int kk = 0; kk < 4; ++kk) {
    const float* __restrict__ wp = wb + (size_t)(k4 + kk) * E;
    const float av = (kk == 0) ? a.x : (kk == 1) ? a.y : (kk == 2) ? a.z : a.w;
#pragma unroll
    for (int j = 0; j < 16; ++j) acc[j] = fmaf(av, wp[j], acc[j]);
  }
  float* pr = part + (size_t)blockIdx.y * (size_t)T * E + (size_t)m * E + eo;
#pragma unroll
  for (int j = 0; j < 4; ++j)
    *(float4*)&pr[j * 4] = make_float4(acc[4 * j], acc[4 * j + 1], acc[4 * j + 2], acc[4 * j + 3]);
}

}  // namespace

extern "C" void kernel_launch(void* const* d_in, const int* in_sizes, int n_in,
                              void* d_out, int out_size, void* d_ws, size_t ws_size,
                              hipStream_t stream) {
  const float* A    = (const float*)d_in[0];
  const float* W    = (const float*)d_in[1];
  const float* bias = (const float*)d_in[2];
  float* out = (float*)d_out;

  if (ws_size >= WS_NEW) {
    char*  wt   = (char*)d_ws;
    float* part = (float*)((char*)d_ws + WSPLIT_BYTES);
    hipLaunchKernelGGL(wsplit, dim3(1792), dim3(256), 0, stream, W, wt);
    hipLaunchKernelGGL(gemm_f16, dim3(2, 128, 2), dim3(256), 0, stream, A, wt, part);
    hipLaunchKernelGGL(routing, dim3(T / 32), dim3(1024), 0, stream, part, bias, out, KS);
  } else {
    const int nks = (ws_size >= WS_KS4) ? 4 : 1;
    float* Wt   = (float*)d_ws;
    float* part = (float*)((char*)d_ws + WT_BYTES);
    hipLaunchKernelGGL(transposeW, dim3(H / 32, E / 32), dim3(256), 0, stream, W, Wt);
    hipLaunchKernelGGL(gemm_ks, dim3(4, nks, 128), dim3(256), 0, stream, A, Wt, part);
    hipLaunchKernelGGL(routing, dim3(T / 32), dim3(1024), 0, stream, part, bias, out, nks);
  }
}